// Round 10
// baseline (79.111 us; speedup 1.0000x reference)
//
#include <hip/hip_runtime.h>

#define NUM_HEADS 8
#define DIM 64
#define NCLUST 512
#define NTOK 16384          // 8*2048 tokens
#define ROWLEN 512          // NUM_HEADS*DIM floats per token row
#define NIDS (NTOK * NUM_HEADS)           // 131072
#define NMEANS (NUM_HEADS * NCLUST * DIM) // 262144
#define NCK (NUM_HEADS * NCLUST)          // 4096
#define TPB 128             // tokens per block in the fused score kernel
#define KQ 128              // clusters per staged quarter
#define CAP 8               // candidate slots per token (incl. winner)
#define DELTA 0.35f         // ~19 sigma of bf16 coarse-score noise + pack quant

typedef unsigned long long u64;
typedef short bf16x8 __attribute__((ext_vector_type(8)));
typedef float f32x4 __attribute__((ext_vector_type(4)));

__device__ __forceinline__ unsigned short f2bf(float f) {   // RNE f32->bf16 bits
    unsigned b = __float_as_uint(f);
    return (unsigned short)((b + 0x7fffu + ((b >> 16) & 1u)) >> 16);
}
__device__ __forceinline__ unsigned pack2bf(float lo, float hi) {
    return (unsigned)f2bf(lo) | ((unsigned)f2bf(hi) << 16);
}
__device__ __forceinline__ float bf2f(unsigned short b) {
    return __uint_as_float((unsigned)b << 16);
}
__device__ __forceinline__ u64 packkey(float s, int k) {    // u64 MIN == max s, tie -> min k
    unsigned u = __float_as_uint(s);
    unsigned ord = (u & 0x80000000u) ? ~u : (u | 0x80000000u);
    return ((u64)(~ord) << 32) | (unsigned)k;
}
// swizzled byte offset into a [rows][128B] LDS tile (G4 XOR pattern)
__device__ __forceinline__ int swz(int row, int byte_in_row) {
    return row * 128 + (byte_in_row ^ ((row & 7) << 4));
}

// ---------------- kernel 0: fused prep: q = 0.5*|m|^2 and means f32->bf16 ----
__global__ void vq_prep(const float* __restrict__ means,
                        float* __restrict__ q,
                        unsigned short* __restrict__ mbf) {
    int g = blockIdx.x * blockDim.x + threadIdx.x;   // 0..65535
    int row = g >> 4, c = g & 15;
    float4 v = *(const float4*)(means + (size_t)row * DIM + c * 4);
    ushort4 b;
    b.x = f2bf(v.x); b.y = f2bf(v.y); b.z = f2bf(v.z); b.w = f2bf(v.w);
    *(ushort4*)(mbf + (size_t)row * DIM + c * 4) = b;
    float s = fmaf(v.x, v.x, fmaf(v.y, v.y, fmaf(v.z, v.z, v.w * v.w)));
#pragma unroll
    for (int off = 1; off < 16; off <<= 1) s += __shfl_xor(s, off, 64);
    if (c == 0) q[row] = 0.5f * s;
}

// ---------------- kernel 1: fused coarse MFMA + candidates + rescore + SCATTER ----
// Two-sweep exact-candidate scheme (validated r7-r9). Epilogue now also does the
// EMA scatter: the 16-lane rescore group already holds x row (float4/lane, dims
// 4lc..4lc+3) and the winning id in all lanes -> 2 pk_add_bf16 atomics per lane,
// one count atomic per token. Deletes the standalone vq_scatter kernel and its
// 32MB x re-read. LDS ~37.4KB -> 4 blocks/CU.
__global__ __launch_bounds__(256, 4) void vq_score(const float* __restrict__ x,
                                                   const float* __restrict__ means,
                                                   const unsigned short* __restrict__ mbf,
                                                   const float* __restrict__ q,
                                                   float* __restrict__ ids_f,
                                                   float* __restrict__ counts,
                                                   unsigned short* __restrict__ sums_bf,
                                                   int rep_mask) {
    __shared__ __align__(16) unsigned char msq[KQ * 128];    // 16 KB means quarter (swz)
    __shared__ __align__(16) unsigned char xbb[TPB * 128];   // 16 KB x tile (swz)
    __shared__ float qs[NCLUST];                             // 2 KB
    __shared__ int cnt[TPB];                                 // 0.5 KB
    __shared__ unsigned short candL[TPB][CAP];               // 2 KB

    const int head = blockIdx.y;
    const int t0   = blockIdx.x * TPB;
    const int tid  = threadIdx.x;
    const int wv = tid >> 6, l = tid & 63;
    const int lg = l >> 4, lc = l & 15;
    const int twave = wv * 32;

    uint4 pf0, pf1, pf2, pf3;            // prefetch registers for one means quarter
    auto loadq = [&](int qt) {
        int row = tid >> 1, c = tid & 1;
        const uint4* src = (const uint4*)(mbf +
            ((size_t)head * NCLUST + qt * KQ + row) * DIM + c * 32);
        pf0 = src[0]; pf1 = src[1]; pf2 = src[2]; pf3 = src[3];
    };
    auto writems = [&]() {
        int row = tid >> 1, c = tid & 1;
        *(uint4*)(msq + swz(row, c * 64 + 0))  = pf0;
        *(uint4*)(msq + swz(row, c * 64 + 16)) = pf1;
        *(uint4*)(msq + swz(row, c * 64 + 32)) = pf2;
        *(uint4*)(msq + swz(row, c * 64 + 48)) = pf3;
    };

    // ---- stage x tile (f32 -> bf16, swizzled) ----
#pragma unroll
    for (int it = 0; it < 2; ++it) {
        int tok = (tid >> 2) + it * 64;
        int c = tid & 3;                 // 16 dims = 64B f32 -> 32B bf16
        const float4* src = (const float4*)(x + (size_t)(t0 + tok) * ROWLEN + head * DIM + c * 16);
        float4 v0 = src[0], v1 = src[1], v2 = src[2], v3 = src[3];
        uint4 lo, hi;
        lo.x = pack2bf(v0.x, v0.y); lo.y = pack2bf(v0.z, v0.w);
        lo.z = pack2bf(v1.x, v1.y); lo.w = pack2bf(v1.z, v1.w);
        hi.x = pack2bf(v2.x, v2.y); hi.y = pack2bf(v2.z, v2.w);
        hi.z = pack2bf(v3.x, v3.y); hi.w = pack2bf(v3.z, v3.w);
        *(uint4*)(xbb + swz(tok, c * 32 + 0))  = lo;
        *(uint4*)(xbb + swz(tok, c * 32 + 16)) = hi;
    }
    // ---- stage q, zero cnt, prefetch quarter 0 ----
    qs[tid] = q[head * NCLUST + tid];
    qs[tid + 256] = q[head * NCLUST + tid + 256];
    if (tid < TPB) cnt[tid] = 0;
    loadq(0);
    __syncthreads();

    // ---- A fragments from LDS (kept live across both sweeps) ----
    bf16x8 af[2][2];
#pragma unroll
    for (int tt = 0; tt < 2; ++tt)
#pragma unroll
        for (int ks = 0; ks < 2; ++ks)
            af[tt][ks] = *(const bf16x8*)(xbb + swz(twave + tt * 16 + lc, ks * 64 + lg * 16));

    float best[2][4];
#pragma unroll
    for (int tt = 0; tt < 2; ++tt)
#pragma unroll
        for (int r = 0; r < 4; ++r) best[tt][r] = -3.0e38f;
    float thr[2][4];

    auto sweep1_q = [&](int qt) {
        const int rbase = 511 - qt * KQ - lc;
#pragma unroll
        for (int ct = 0; ct < KQ / 16; ++ct) {
            bf16x8 b0 = *(const bf16x8*)(msq + swz(ct * 16 + lc, 0 + lg * 16));
            bf16x8 b1 = *(const bf16x8*)(msq + swz(ct * 16 + lc, 64 + lg * 16));
            float qv = qs[qt * KQ + ct * 16 + lc];
            int rk = rbase - ct * 16;
#pragma unroll
            for (int tt = 0; tt < 2; ++tt) {
                f32x4 acc = (f32x4){-qv, -qv, -qv, -qv};   // C-in = -q_k: acc out == score
                acc = __builtin_amdgcn_mfma_f32_16x16x32_bf16(af[tt][0], b0, acc, 0, 0, 0);
                acc = __builtin_amdgcn_mfma_f32_16x16x32_bf16(af[tt][1], b1, acc, 0, 0, 0);
#pragma unroll
                for (int r = 0; r < 4; ++r) {
                    float v = __uint_as_float((__float_as_uint(acc[r]) & 0xFFFFFE00u) | (unsigned)rk);
                    best[tt][r] = fmaxf(best[tt][r], v);
                }
            }
        }
    };
    auto collect_q = [&](int qt) {
#pragma unroll
        for (int ct = 0; ct < KQ / 16; ++ct) {
            bf16x8 b0 = *(const bf16x8*)(msq + swz(ct * 16 + lc, 0 + lg * 16));
            bf16x8 b1 = *(const bf16x8*)(msq + swz(ct * 16 + lc, 64 + lg * 16));
            float qv = qs[qt * KQ + ct * 16 + lc];
            int k = qt * KQ + ct * 16 + lc;
#pragma unroll
            for (int tt = 0; tt < 2; ++tt) {
                f32x4 acc = (f32x4){-qv, -qv, -qv, -qv};
                acc = __builtin_amdgcn_mfma_f32_16x16x32_bf16(af[tt][0], b0, acc, 0, 0, 0);
                acc = __builtin_amdgcn_mfma_f32_16x16x32_bf16(af[tt][1], b1, acc, 0, 0, 0);
#pragma unroll
                for (int r = 0; r < 4; ++r) {
                    if (acc[r] >= thr[tt][r]) {
                        int tok = twave + tt * 16 + lg * 4 + r;
                        int slot = atomicAdd(&cnt[tok], 1);
                        if (slot < CAP) candL[tok][slot] = (unsigned short)k;
                    }
                }
            }
        }
    };

    // ================= sweep 1 (quarters 0..3, prefetched) =================
    for (int qt = 0; qt < 4; ++qt) {
        __syncthreads();                  // readers done with previous msq content
        writems();                        // waits on loadq's vmcnt automatically
        if (qt < 3) loadq(qt + 1);        // next quarter in flight during compute
        __syncthreads();
        sweep1_q(qt);
    }
    // butterfly across the 16 cluster-lanes; all lanes converge to token max
#pragma unroll
    for (int tt = 0; tt < 2; ++tt)
#pragma unroll
        for (int r = 0; r < 4; ++r) {
#pragma unroll
            for (int off = 1; off < 16; off <<= 1)
                best[tt][r] = fmaxf(best[tt][r], __shfl_xor(best[tt][r], off, 64));
            thr[tt][r] = best[tt][r] - DELTA;
        }

    // ================= sweep 2 (reverse order: q3 already staged) ============
    loadq(2);
    collect_q(3);                         // msq still holds quarter 3 (read-only reuse)
    for (int qt = 2; qt >= 0; --qt) {
        __syncthreads();
        writems();
        if (qt > 0) loadq(qt - 1);
        __syncthreads();
        collect_q(qt);
    }
    __syncthreads();

    // ========== exact f32 rescore + fused EMA scatter ==========
    // 16-lane subgroup per token (lane lc = dims 4lc..4lc+3).
#pragma unroll 2
    for (int g = 0; g < 8; ++g) {
        int tok = twave + g * 4 + lg;
        int n = cnt[tok]; n = n < CAP ? n : CAP;
        const float4 xv = *(const float4*)(x + (size_t)(t0 + tok) * ROWLEN + head * DIM + lc * 4);
        u64 bk = ~0ull;
        for (int j = 0; j < n; ++j) {
            int k = candL[tok][j];
            const float4 mv = *(const float4*)(means + ((size_t)head * NCLUST + k) * DIM + lc * 4);
            float p = fmaf(xv.x, mv.x, fmaf(xv.y, mv.y, fmaf(xv.z, mv.z, xv.w * mv.w)));
#pragma unroll
            for (int off = 1; off < 16; off <<= 1) p += __shfl_xor(p, off, 64);
            u64 cd = packkey(p - qs[k], k);
            bk = cd < bk ? cd : bk;
        }
        // all 16 lanes hold the winning key
        int id = (int)(unsigned)(bk & 0x1ffu);
        int token = t0 + tok;
        int rep = token & rep_mask;
        if (lc == 0) {
            ids_f[(size_t)token * NUM_HEADS + head] = (float)id;
            atomicAdd(&counts[rep * NCK + head * NCLUST + id], 1.0f);
        }
        unsigned short* dst = sums_bf + (size_t)rep * NMEANS
                            + (((size_t)head * NCLUST + id) << 6) + lc * 4;
        unsigned v0 = pack2bf(xv.x, xv.y);
        unsigned v1 = pack2bf(xv.z, xv.w);
        asm volatile("global_atomic_pk_add_bf16 %0, %1, off" :: "v"(dst),     "v"(v0) : "memory");
        asm volatile("global_atomic_pk_add_bf16 %0, %1, off" :: "v"(dst + 2), "v"(v1) : "memory");
    }
}

// ---------------- kernel 3: EMA finalize (sums replicas, bf16) ----------------
__global__ void vq_final(const float* __restrict__ means,
                         const float* __restrict__ counts,
                         const unsigned short* __restrict__ sums_bf,
                         float* __restrict__ out_means,
                         int nrep) {
    int i = blockIdx.x * blockDim.x + threadIdx.x;   // 0..262143
    int ck = i >> 6;
    float c = 0.f, s = 0.f;
    for (int r = 0; r < nrep; ++r) {
        c += counts[r * NCK + ck];
        s += bf2f(sums_bf[(size_t)r * NMEANS + i]);
    }
    float nm = s / (1e-6f + c);
    out_means[i] = 0.999f * means[i] + 0.001f * nm;
}

extern "C" void kernel_launch(void* const* d_in, const int* in_sizes, int n_in,
                              void* d_out, int out_size, void* d_ws, size_t ws_size,
                              hipStream_t stream) {
    const float* x     = (const float*)d_in[0];   // [8,2048,512]
    const float* means = (const float*)d_in[1];   // [8,512,64]

    float* out       = (float*)d_out;
    float* ids_f     = out;            // 131072 floats (cluster ids as float)
    float* out_means = out + NIDS;     // 262144 floats

    // ---- workspace layout ----
    float*          q   = (float*)d_ws;                 // NCK f32 (16 KB)
    unsigned short* mbf = (unsigned short*)(q + NCK);   // NMEANS u16 (512 KB)
    float*          fbase = (float*)(mbf + NMEANS);
    size_t core = (size_t)((char*)fbase - (char*)d_ws);

    size_t per_rep = (size_t)NCK * sizeof(float) + (size_t)NMEANS * sizeof(unsigned short);
    int nrep = 1;
    for (int r = 8; r > 1; r >>= 1) {
        if (ws_size >= core + (size_t)r * per_rep) { nrep = r; break; }
    }
    float*          counts  = fbase;                                   // nrep*NCK f32
    unsigned short* sums_bf = (unsigned short*)(counts + (size_t)nrep * NCK); // nrep*NMEANS u16

    hipMemsetAsync(counts, 0, (size_t)nrep * per_rep, stream);

    vq_prep<<<(NCK * 16) / 256, 256, 0, stream>>>(means, q, mbf);

    dim3 gs(NTOK / TPB, NUM_HEADS);
    vq_score<<<gs, 256, 0, stream>>>(x, means, mbf, q, ids_f, counts, sums_bf, nrep - 1);

    vq_final<<<NMEANS / 256, 256, 0, stream>>>(means, counts, sums_bf, out_means, nrep);
}